// Round 2
// baseline (443.422 us; speedup 1.0000x reference)
//
#include <hip/hip_runtime.h>
#include <math.h>

#define HD 4096  // H == D == 4096

// Async global->LDS, 16 B per lane, hardware-queued (bypasses L1/VGPRs).
__device__ __forceinline__ void gload16(const float* g, float* l) {
    __builtin_amdgcn_global_load_lds(
        (const __attribute__((address_space(1))) void*)g,
        (__attribute__((address_space(3))) void*)l,
        16, 0, 0);
}

// ---------------------------------------------------------------------------
// Kernel 1: 6-way GEMV via global_load_lds double-buffered streaming.
// Grid: 1536 blocks x 256 threads. mat = bid>>8 (block-uniform), 16 rows/block.
// Each wave owns 4 contiguous rows (one linear 64 KB weight stream), staged
// into wave-private LDS as 16 chunks of 4 KB, double-buffered with a counted
// s_waitcnt vmcnt(4) — NO __syncthreads in the loop, so the next chunk's DMA
// stays in flight across the compute. x is held in 16 float4 registers.
// ---------------------------------------------------------------------------
__global__ __launch_bounds__(256, 4) void k_gemv(
    const float* __restrict__ x,
    const float* __restrict__ Wq, const float* __restrict__ Wk,
    const float* __restrict__ Wv, const float* __restrict__ Wi,
    const float* __restrict__ Wf, const float* __restrict__ Wo,
    float* __restrict__ ws_dots)
{
    __shared__ float buf[4][2][1024];   // [wave][parity][4 KB chunk]
    const int tid  = threadIdx.x;
    const int wave = tid >> 6;
    const int lane = tid & 63;
    const int mat  = blockIdx.x >> 8;            // 0..5, block-uniform
    const int base = (blockIdx.x & 255) << 4;    // 16 rows per block
    const int srow = base + (wave << 2);         // this wave's first row

    const float* W = Wq;
    if      (mat == 1) W = Wk;
    else if (mat == 2) W = Wv;
    else if (mat == 3) W = Wi;
    else if (mat == 4) W = Wf;
    else if (mat == 5) W = Wo;

    const float* Ws = W + (size_t)srow * HD;     // 4 rows = 64 KB contiguous

    // x -> 16 float4 regs; xr[(c&3)*4+j] pairs with chunk element j*256+lane*4
    const float4* x4 = (const float4*)x;
    float4 xr[16];
#pragma unroll
    for (int k = 0; k < 16; ++k)
        xr[k] = x4[((k >> 2) << 8) + ((k & 3) << 6) + lane];

    float* mybuf = &buf[wave][0][0];

    // Prologue: stage chunk 0 (4 x 1 KB DMA).
#pragma unroll
    for (int j = 0; j < 4; ++j)
        gload16(Ws + (j << 8) + (lane << 2), mybuf + (j << 8));

    float acc = 0.f;
#pragma unroll
    for (int c = 0; c < 16; ++c) {
        // All my LDS reads of the buffer being overwritten must be complete.
        asm volatile("s_waitcnt lgkmcnt(0)" ::: "memory");
        if (c < 15) {
            const float* src = Ws + ((c + 1) << 10) + (lane << 2);
            float*       dst = mybuf + (((c + 1) & 1) << 10);
#pragma unroll
            for (int j = 0; j < 4; ++j)
                gload16(src + (j << 8), dst + (j << 8));
            // Wait chunk c complete; chunk c+1's 4 DMAs stay outstanding.
            asm volatile("s_waitcnt vmcnt(4)" ::: "memory");
        } else {
            asm volatile("s_waitcnt vmcnt(0)" ::: "memory");
        }

        const float* cb = mybuf + ((c & 1) << 10);
#pragma unroll
        for (int j = 0; j < 4; ++j) {
            float4 w  = *(const float4*)(cb + (j << 8) + (lane << 2));
            float4 xv = xr[((c & 3) << 2) + j];
            acc += w.x * xv.x + w.y * xv.y + w.z * xv.z + w.w * xv.w;
        }

        if ((c & 3) == 3) {  // row boundary: reduce + store, reset acc
            float r = acc;
#pragma unroll
            for (int off = 32; off > 0; off >>= 1)
                r += __shfl_xor(r, off, 64);
            if (lane == 0)
                ws_dots[(mat << 12) | (srow + (c >> 2))] = r;
            acc = 0.f;
        }
    }
}

// ---------------------------------------------------------------------------
// Kernel 2: gate math for all 4096 rows + per-block partials of n_t . q.
// 16 blocks x 256 threads, one row per thread, fully coalesced.
// ---------------------------------------------------------------------------
__global__ __launch_bounds__(256) void k_gates(
    const float* __restrict__ ws_dots,
    const float* __restrict__ bq, const float* __restrict__ bk,
    const float* __restrict__ bv, const float* __restrict__ bi,
    const float* __restrict__ bf, const float* __restrict__ bo,
    const float* __restrict__ n_prev, const float* __restrict__ m_prev,
    float* __restrict__ ws_q, float* __restrict__ ws_v,
    float* __restrict__ ws_o, float* __restrict__ ws_fg,
    float* __restrict__ ws_ik,
    float* __restrict__ out_n, float* __restrict__ out_m,
    float* __restrict__ ws_nq)
{
    const int tid = threadIdx.x;
    const int row = blockIdx.x * 256 + tid;

    float dq  = ws_dots[0 * HD + row];
    float dk  = ws_dots[1 * HD + row];
    float dv  = ws_dots[2 * HD + row];
    float di  = ws_dots[3 * HD + row];
    float df  = ws_dots[4 * HD + row];
    float d_o = ws_dots[5 * HD + row];

    float q  = dq + bq[row];
    float k  = (dk + bk[row]) * (1.0f / 64.0f);   // 1/sqrt(4096)
    float v  = dv + bv[row];
    float o  = 1.0f / (1.0f + expf(-(d_o + bo[row])));
    float it = di + bi[row];
    float ft = df + bf[row];
    float mp = m_prev[row];
    float mt = fmaxf(ft + mp, it);
    float ig = expf(it - mt);
    float fg = expf(ft + mp - mt);
    float nt = fg * n_prev[row] + ig * k;

    ws_q[row]  = q;
    ws_v[row]  = v;
    ws_o[row]  = o;
    ws_fg[row] = fg;
    ws_ik[row] = ig * k;
    out_n[row] = nt;
    out_m[row] = mt;

    float acc = nt * q;
#pragma unroll
    for (int off = 32; off > 0; off >>= 1)
        acc += __shfl_xor(acc, off, 64);
    __shared__ float red[4];
    if ((tid & 63) == 0) red[tid >> 6] = acc;
    __syncthreads();
    if (tid == 0) ws_nq[blockIdx.x] = red[0] + red[1] + red[2] + red[3];
}

// ---------------------------------------------------------------------------
// Kernel 3: c_t = f_g[c]*c_prev[r][c] + ik[c]*v[r], fused with
// h_t[r] = o[r] * (c_t[r,:] . q) / denom.  One block per row.
// ---------------------------------------------------------------------------
__global__ __launch_bounds__(256) void k_ct(
    const float* __restrict__ c_prev,
    const float* __restrict__ ws_q, const float* __restrict__ ws_v,
    const float* __restrict__ ws_o, const float* __restrict__ ws_fg,
    const float* __restrict__ ws_ik, const float* __restrict__ ws_nq,
    float* __restrict__ out_h, float* __restrict__ out_c)
{
    const int row = blockIdx.x;
    const int tid = threadIdx.x;
    const float vr = ws_v[row];

    const float4* cp4 = (const float4*)(c_prev + (size_t)row * HD);
    float4*       ct4 = (float4*)(out_c + (size_t)row * HD);
    const float4* fg4 = (const float4*)ws_fg;
    const float4* ik4 = (const float4*)ws_ik;
    const float4* q4  = (const float4*)ws_q;

    float4 c[4], f[4], k[4], qv[4];
#pragma unroll
    for (int t = 0; t < 4; ++t) {
        const int idx = t * 256 + tid;
        c[t]  = cp4[idx];
        f[t]  = fg4[idx];
        k[t]  = ik4[idx];
        qv[t] = q4[idx];
    }

    float acc = 0.f;
#pragma unroll
    for (int t = 0; t < 4; ++t) {
        const int idx = t * 256 + tid;
        float4 ct;
        ct.x = f[t].x * c[t].x + k[t].x * vr;
        ct.y = f[t].y * c[t].y + k[t].y * vr;
        ct.z = f[t].z * c[t].z + k[t].z * vr;
        ct.w = f[t].w * c[t].w + k[t].w * vr;
        ct4[idx] = ct;
        acc += ct.x * qv[t].x + ct.y * qv[t].y + ct.z * qv[t].z + ct.w * qv[t].w;
    }
#pragma unroll
    for (int off = 32; off > 0; off >>= 1) acc += __shfl_xor(acc, off, 64);
    __shared__ float red[4];
    if ((tid & 63) == 0) red[tid >> 6] = acc;
    __syncthreads();
    if (tid == 0) {
        float s = red[0] + red[1] + red[2] + red[3];
        float d = 0.f;
#pragma unroll
        for (int i = 0; i < 16; ++i) d += ws_nq[i];
        float den = fmaxf(fabsf(d), 1.0f);
        out_h[row] = ws_o[row] * s / den;
    }
}

// ---------------------------------------------------------------------------
extern "C" void kernel_launch(void* const* d_in, const int* in_sizes, int n_in,
                              void* d_out, int out_size, void* d_ws, size_t ws_size,
                              hipStream_t stream) {
    const float* x      = (const float*)d_in[0];
    /* d_in[1] = h_prev: unused by the reference */
    const float* c_prev = (const float*)d_in[2];
    const float* n_prev = (const float*)d_in[3];
    const float* m_prev = (const float*)d_in[4];
    const float* Wq = (const float*)d_in[5];  const float* bq = (const float*)d_in[6];
    const float* Wk = (const float*)d_in[7];  const float* bk = (const float*)d_in[8];
    const float* Wv = (const float*)d_in[9];  const float* bv = (const float*)d_in[10];
    const float* Wi = (const float*)d_in[11]; const float* bi = (const float*)d_in[12];
    const float* Wf = (const float*)d_in[13]; const float* bf = (const float*)d_in[14];
    const float* Wo = (const float*)d_in[15]; const float* bo = (const float*)d_in[16];

    // Output layout: h_t [H], c_t [H,H], n_t [H], m_t [H] — flat concat.
    float* out   = (float*)d_out;
    float* out_h = out;
    float* out_c = out + HD;
    float* out_n = out + HD + (size_t)HD * HD;
    float* out_m = out_n + HD;

    // Workspace layout (floats): dots[6*HD], q, v, o, f_g, i_g*k, nq[16]
    float* ws      = (float*)d_ws;
    float* ws_dots = ws;
    float* ws_q    = ws + 6 * HD;
    float* ws_v    = ws + 7 * HD;
    float* ws_o    = ws + 8 * HD;
    float* ws_fg   = ws + 9 * HD;
    float* ws_ik   = ws + 10 * HD;
    float* ws_nq   = ws + 11 * HD;   // 16 floats

    k_gemv<<<1536, 256, 0, stream>>>(x, Wq, Wk, Wv, Wi, Wf, Wo, ws_dots);
    k_gates<<<16, 256, 0, stream>>>(ws_dots, bq, bk, bv, bi, bf, bo,
                                    n_prev, m_prev,
                                    ws_q, ws_v, ws_o, ws_fg, ws_ik,
                                    out_n, out_m, ws_nq);
    k_ct<<<HD, 256, 0, stream>>>(c_prev, ws_q, ws_v, ws_o, ws_fg, ws_ik,
                                 ws_nq, out_h, out_c);
}

// Round 4
// 430.490 us; speedup vs baseline: 1.0300x; 1.0300x over previous
//
#include <hip/hip_runtime.h>
#include <math.h>

#define HD 4096  // H == D == 4096

typedef float v4f __attribute__((ext_vector_type(4)));  // clang-native for nt builtins

// ---------------------------------------------------------------------------
// Kernel 1: 6-way GEMV, one wave per (matrix, row).  (Round-1 version: best
// measured variant; at the ~3.2 TB/s streaming-read ceiling.)
// Grid: 6144 blocks x 256 threads. Blocks [m*1024, (m+1)*1024) handle matrix m.
// ---------------------------------------------------------------------------
__global__ __launch_bounds__(256, 6) void k_gemv(
    const float* __restrict__ x,
    const float* __restrict__ Wq, const float* __restrict__ Wk,
    const float* __restrict__ Wv, const float* __restrict__ Wi,
    const float* __restrict__ Wf, const float* __restrict__ Wo,
    float* __restrict__ ws_dots)
{
    __shared__ float xs[HD];
    const int tid = threadIdx.x;
    {
        const float4* x4  = (const float4*)x;
        float4*       sx4 = (float4*)xs;
#pragma unroll
        for (int i = 0; i < 4; ++i) sx4[i * 256 + tid] = x4[i * 256 + tid];
    }
    __syncthreads();

    const int wave = tid >> 6;
    const int lane = tid & 63;
    const int mat  = blockIdx.x >> 10;                       // 0..5, block-uniform
    const int row  = ((blockIdx.x & 1023) << 2) | wave;      // 0..4095

    const float* W = Wq;
    if      (mat == 1) W = Wk;
    else if (mat == 2) W = Wv;
    else if (mat == 3) W = Wi;
    else if (mat == 4) W = Wf;
    else if (mat == 5) W = Wo;

    const float4* Wrow = (const float4*)(W + (size_t)row * HD) + lane;
    const float4* sx4  = (const float4*)xs + lane;

    float a0 = 0.f, a1 = 0.f;
#pragma unroll
    for (int t = 0; t < 16; t += 2) {
        float4 w0 = Wrow[t * 64];
        float4 x0 = sx4[t * 64];
        float4 w1 = Wrow[(t + 1) * 64];
        float4 x1 = sx4[(t + 1) * 64];
        a0 += w0.x * x0.x + w0.y * x0.y + w0.z * x0.z + w0.w * x0.w;
        a1 += w1.x * x1.x + w1.y * x1.y + w1.z * x1.z + w1.w * x1.w;
    }
    float acc = a0 + a1;
#pragma unroll
    for (int off = 32; off > 0; off >>= 1)
        acc += __shfl_xor(acc, off, 64);

    if (lane == 0) ws_dots[(mat << 12) | row] = acc;
}

// ---------------------------------------------------------------------------
// Kernel 2: gate math for all 4096 rows + per-block partials of n_t . q.
// 16 blocks x 256 threads, one row per thread, fully coalesced.
// ---------------------------------------------------------------------------
__global__ __launch_bounds__(256) void k_gates(
    const float* __restrict__ ws_dots,
    const float* __restrict__ bq, const float* __restrict__ bk,
    const float* __restrict__ bv, const float* __restrict__ bi,
    const float* __restrict__ bf, const float* __restrict__ bo,
    const float* __restrict__ n_prev, const float* __restrict__ m_prev,
    float* __restrict__ ws_q, float* __restrict__ ws_v,
    float* __restrict__ ws_o, float* __restrict__ ws_fg,
    float* __restrict__ ws_ik,
    float* __restrict__ out_n, float* __restrict__ out_m,
    float* __restrict__ ws_nq)
{
    const int tid = threadIdx.x;
    const int row = blockIdx.x * 256 + tid;

    float dq  = ws_dots[0 * HD + row];
    float dk  = ws_dots[1 * HD + row];
    float dv  = ws_dots[2 * HD + row];
    float di  = ws_dots[3 * HD + row];
    float df  = ws_dots[4 * HD + row];
    float d_o = ws_dots[5 * HD + row];

    float q  = dq + bq[row];
    float k  = (dk + bk[row]) * (1.0f / 64.0f);   // 1/sqrt(4096)
    float v  = dv + bv[row];
    float o  = 1.0f / (1.0f + expf(-(d_o + bo[row])));
    float it = di + bi[row];
    float ft = df + bf[row];
    float mp = m_prev[row];
    float mt = fmaxf(ft + mp, it);
    float ig = expf(it - mt);
    float fg = expf(ft + mp - mt);
    float nt = fg * n_prev[row] + ig * k;

    ws_q[row]  = q;
    ws_v[row]  = v;
    ws_o[row]  = o;
    ws_fg[row] = fg;
    ws_ik[row] = ig * k;
    out_n[row] = nt;
    out_m[row] = mt;

    float acc = nt * q;
#pragma unroll
    for (int off = 32; off > 0; off >>= 1)
        acc += __shfl_xor(acc, off, 64);
    __shared__ float red[4];
    if ((tid & 63) == 0) red[tid >> 6] = acc;
    __syncthreads();
    if (tid == 0) ws_nq[blockIdx.x] = red[0] + red[1] + red[2] + red[3];
}

// ---------------------------------------------------------------------------
// Kernel 3: c_t = f_g[c]*c_prev[r][c] + ik[c]*v[r], fused with
// h_t[r] = o[r] * (c_t[r,:] . q) / denom.  2 rows per block, 2048 blocks.
// c_prev loads and out_c stores are NON-TEMPORAL: neither is reused this
// iteration, and letting them allocate evicts ~128 MB of weights from the
// Infinity Cache (the suspected cause of k_gemv's 50% L3 hit rate).
// denom is summed by ALL threads up front, overlapped with streaming loads.
// ---------------------------------------------------------------------------
__global__ __launch_bounds__(256) void k_ct(
    const float* __restrict__ c_prev,
    const float* __restrict__ ws_q, const float* __restrict__ ws_v,
    const float* __restrict__ ws_o, const float* __restrict__ ws_fg,
    const float* __restrict__ ws_ik, const float* __restrict__ ws_nq,
    float* __restrict__ out_h, float* __restrict__ out_c)
{
    const int row0 = blockIdx.x << 1;
    const int tid  = threadIdx.x;

    float den = 0.f;
#pragma unroll
    for (int i = 0; i < 16; ++i) den += ws_nq[i];
    den = fmaxf(fabsf(den), 1.0f);

    const float v0 = ws_v[row0];
    const float v1 = ws_v[row0 + 1];

    const v4f* cp0 = (const v4f*)(c_prev + (size_t)row0 * HD);
    const v4f* cp1 = cp0 + HD / 4;
    v4f*       ct0 = (v4f*)(out_c + (size_t)row0 * HD);
    v4f*       ct1 = ct0 + HD / 4;
    const v4f* fg4 = (const v4f*)ws_fg;
    const v4f* ik4 = (const v4f*)ws_ik;
    const v4f* q4  = (const v4f*)ws_q;

    v4f c0[4], c1[4], f[4], k[4], qv[4];
#pragma unroll
    for (int t = 0; t < 4; ++t) {
        const int idx = t * 256 + tid;
        c0[t] = __builtin_nontemporal_load(&cp0[idx]);
        c1[t] = __builtin_nontemporal_load(&cp1[idx]);
        f[t]  = fg4[idx];
        k[t]  = ik4[idx];
        qv[t] = q4[idx];
    }

    float acc0 = 0.f, acc1 = 0.f;
#pragma unroll
    for (int t = 0; t < 4; ++t) {
        const int idx = t * 256 + tid;
        v4f a = f[t] * c0[t] + k[t] * v0;
        v4f b = f[t] * c1[t] + k[t] * v1;
        __builtin_nontemporal_store(a, &ct0[idx]);
        __builtin_nontemporal_store(b, &ct1[idx]);
        acc0 += a.x * qv[t].x + a.y * qv[t].y + a.z * qv[t].z + a.w * qv[t].w;
        acc1 += b.x * qv[t].x + b.y * qv[t].y + b.z * qv[t].z + b.w * qv[t].w;
    }
#pragma unroll
    for (int off = 32; off > 0; off >>= 1) {
        acc0 += __shfl_xor(acc0, off, 64);
        acc1 += __shfl_xor(acc1, off, 64);
    }
    __shared__ float red[2][4];
    if ((tid & 63) == 0) {
        red[0][tid >> 6] = acc0;
        red[1][tid >> 6] = acc1;
    }
    __syncthreads();
    if (tid == 0) {
        float s0 = red[0][0] + red[0][1] + red[0][2] + red[0][3];
        float s1 = red[1][0] + red[1][1] + red[1][2] + red[1][3];
        out_h[row0]     = ws_o[row0]     * s0 / den;
        out_h[row0 + 1] = ws_o[row0 + 1] * s1 / den;
    }
}

// ---------------------------------------------------------------------------
extern "C" void kernel_launch(void* const* d_in, const int* in_sizes, int n_in,
                              void* d_out, int out_size, void* d_ws, size_t ws_size,
                              hipStream_t stream) {
    const float* x      = (const float*)d_in[0];
    /* d_in[1] = h_prev: unused by the reference */
    const float* c_prev = (const float*)d_in[2];
    const float* n_prev = (const float*)d_in[3];
    const float* m_prev = (const float*)d_in[4];
    const float* Wq = (const float*)d_in[5];  const float* bq = (const float*)d_in[6];
    const float* Wk = (const float*)d_in[7];  const float* bk = (const float*)d_in[8];
    const float* Wv = (const float*)d_in[9];  const float* bv = (const float*)d_in[10];
    const float* Wi = (const float*)d_in[11]; const float* bi = (const float*)d_in[12];
    const float* Wf = (const float*)d_in[13]; const float* bf = (const float*)d_in[14];
    const float* Wo = (const float*)d_in[15]; const float* bo = (const float*)d_in[16];

    // Output layout: h_t [H], c_t [H,H], n_t [H], m_t [H] — flat concat.
    float* out   = (float*)d_out;
    float* out_h = out;
    float* out_c = out + HD;
    float* out_n = out + HD + (size_t)HD * HD;
    float* out_m = out_n + HD;

    // Workspace layout (floats): dots[6*HD], q, v, o, f_g, i_g*k, nq[16]
    float* ws      = (float*)d_ws;
    float* ws_dots = ws;
    float* ws_q    = ws + 6 * HD;
    float* ws_v    = ws + 7 * HD;
    float* ws_o    = ws + 8 * HD;
    float* ws_fg   = ws + 9 * HD;
    float* ws_ik   = ws + 10 * HD;
    float* ws_nq   = ws + 11 * HD;   // 16 floats

    k_gemv<<<6 * 1024, 256, 0, stream>>>(x, Wq, Wk, Wv, Wi, Wf, Wo, ws_dots);
    k_gates<<<16, 256, 0, stream>>>(ws_dots, bq, bk, bv, bi, bf, bo,
                                    n_prev, m_prev,
                                    ws_q, ws_v, ws_o, ws_fg, ws_ik,
                                    out_n, out_m, ws_nq);
    k_ct<<<2048, 256, 0, stream>>>(c_prev, ws_q, ws_v, ws_o, ws_fg, ws_ik,
                                   ws_nq, out_h, out_c);
}